// Round 9
// baseline (219.117 us; speedup 1.0000x reference)
//
#include <hip/hip_runtime.h>
#include <cstdint>
#include <cstddef>

typedef unsigned short u16;
typedef __bf16 bf16x8 __attribute__((ext_vector_type(8)));
typedef float f32x4 __attribute__((ext_vector_type(4)));
typedef u16 u16x4 __attribute__((ext_vector_type(4)));
typedef unsigned int u32x2 __attribute__((ext_vector_type(2)));
typedef unsigned int u32x4 __attribute__((ext_vector_type(4)));

#define DEV __device__ __forceinline__

DEV u16 f2bf(float f) {
    union { float f; unsigned u; } un; un.f = f;
    unsigned u = un.u;
    return (u16)((u + 0x7fffu + ((u >> 16) & 1u)) >> 16);
}

DEV unsigned rbf(float f) {       // RNE-rounded f32 bits; bf16 = bytes 2..3
    union { float f; unsigned u; } un; un.f = f;
    return un.u + 0x7fffu + ((un.u >> 16) & 1u);
}

DEV u16 bf16c(float f) {
    __bf16 b = (__bf16)f;
    u16 r; __builtin_memcpy(&r, &b, 2); return r;
}

DEV f32x4 mfma16(bf16x8 a, bf16x8 b, f32x4 c) {
    return __builtin_amdgcn_mfma_f32_16x16x32_bf16(a, b, c, 0, 0, 0);
}

DEV f32x4 vmax4(f32x4 a, f32x4 b) {
    f32x4 r;
    r[0] = fmaxf(a[0], b[0]); r[1] = fmaxf(a[1], b[1]);
    r[2] = fmaxf(a[2], b[2]); r[3] = fmaxf(a[3], b[3]);
    return r;
}

DEV void async16(const u16* g, u16* l) {
    __builtin_amdgcn_global_load_lds(
        (__attribute__((address_space(1))) unsigned int*)(void*)g,
        (__attribute__((address_space(3))) unsigned int*)(void*)l,
        16, 0, 0);
}

// ---------------- fused prep: x cast + both weight transposes ----------------
DEV void trans_body(const float* __restrict__ src, u16* __restrict__ dst,
                    int R, int C, int bx, int by, int tid, u16 (*t)[65]) {
    const int c0 = bx * 64, r0 = by * 64;
    for (int i = 0; i < 4; ++i) {
        int e = (i * 256 + tid) * 4;
        int r = e >> 6, c = e & 63;
        f32x4 v = *(const f32x4*)(src + (size_t)(r0 + r) * C + (c0 + c));
        t[r][c] = f2bf(v[0]); t[r][c + 1] = f2bf(v[1]);
        t[r][c + 2] = f2bf(v[2]); t[r][c + 3] = f2bf(v[3]);
    }
    __syncthreads();
    for (int i = 0; i < 4; ++i) {
        int e = (i * 256 + tid) * 4;
        int ro = e >> 6, co = e & 63;
        u16x4 v;
        v[0] = t[co][ro]; v[1] = t[co + 1][ro]; v[2] = t[co + 2][ro]; v[3] = t[co + 3][ro];
        *(u16x4*)(dst + (size_t)(c0 + ro) * R + (r0 + co)) = v;
    }
}

__global__ __launch_bounds__(256)
void prep_k(const float* __restrict__ x, const float* __restrict__ wqkv,
            const float* __restrict__ wproj, u16* __restrict__ xb,
            u16* __restrict__ wqkvT, u16* __restrict__ wprojT) {
    __shared__ u16 t[64][65];
    const int bid = blockIdx.x, tid = threadIdx.x;
    if (bid < 2048) {                 // x: fp32 -> bf16, 8 elems/thread (exact cover)
        int i = bid * 256 + tid;
        const float* s = x + (size_t)i * 8;
        f32x4 a = *(const f32x4*)s;
        f32x4 b = *(const f32x4*)(s + 4);
        u16 o[8];
        o[0] = f2bf(a[0]); o[1] = f2bf(a[1]); o[2] = f2bf(a[2]); o[3] = f2bf(a[3]);
        o[4] = f2bf(b[0]); o[5] = f2bf(b[1]); o[6] = f2bf(b[2]); o[7] = f2bf(b[3]);
        u16x4* d = (u16x4*)(xb + (size_t)i * 8);
        d[0] = *(u16x4*)&o[0]; d[1] = *(u16x4*)&o[4];
    } else if (bid < 2816) {          // wqkv [1024][3072] -> wqkvT [3072][1024]
        int i = bid - 2048;
        trans_body(wqkv, wqkvT, 1024, 3072, i % 48, i / 48, tid, t);
    } else {                          // wproj [1024][1024] -> wprojT
        int i = bid - 2816;
        trans_body(wproj, wprojT, 1024, 1024, i % 16, i / 16, tid, t);
    }
}

// ---------------- C[M][N] = A[M][K] @ Bt[N][K]^T, bf16 in, fp32 acc ----------------
// (256,3): cap VGPRs for 3 blocks/CU (m97-level occupancy).
__global__ __launch_bounds__(256, 3)
void gemm_bt(const u16* __restrict__ A, const u16* __restrict__ Bt,
             void* __restrict__ Cout, int M, int N, int K, int lda, int of32) {
    __shared__ alignas(16) u16 As[128 * 32];
    __shared__ alignas(16) u16 Bs[128 * 32];
    const int tid = threadIdx.x;
    const int wave = tid >> 6, lane = tid & 63;
    const int quad = lane >> 4, l16 = lane & 15;
    const int m0 = blockIdx.x * 128, n0 = blockIdx.y * 128;
    const int wm = (wave & 1) * 64, wn = (wave >> 1) * 64;

    const f32x4 zero = {0.f, 0.f, 0.f, 0.f};
    f32x4 acc[4][4];
    for (int i = 0; i < 4; ++i) for (int j = 0; j < 4; ++j) acc[i][j] = zero;

    for (int k0 = 0; k0 < K; k0 += 32) {
        __syncthreads();
        for (int p = 0; p < 2; ++p) {
            int s = p * 256 + tid;
            int row = s >> 2, kcs = s & 3;
            int kc = kcs ^ ((row >> 1) & 3);
            async16(A + (size_t)(m0 + row) * lda + k0 + kc * 8, &As[(p * 256 + wave * 64) * 8]);
            async16(Bt + (size_t)(n0 + row) * K + k0 + kc * 8, &Bs[(p * 256 + wave * 64) * 8]);
        }
        __syncthreads();

        bf16x8 af[4], bfr[4];
        for (int mt = 0; mt < 4; ++mt) {
            int row = wm + mt * 16 + l16;
            int ci = (row << 2) | (quad ^ ((row >> 1) & 3));
            af[mt] = *(const bf16x8*)&As[ci * 8];
        }
        for (int nt = 0; nt < 4; ++nt) {
            int col = wn + nt * 16 + l16;
            int ci = (col << 2) | (quad ^ ((col >> 1) & 3));
            bfr[nt] = *(const bf16x8*)&Bs[ci * 8];
        }
        for (int mt = 0; mt < 4; ++mt)
            for (int nt = 0; nt < 4; ++nt)
                acc[mt][nt] = mfma16(af[mt], bfr[nt], acc[mt][nt]);
    }

    for (int mt = 0; mt < 4; ++mt)
        for (int r = 0; r < 4; ++r) {
            int row = m0 + wm + mt * 16 + quad * 4 + r;
            if (of32) {
                float* crow = (float*)Cout + (size_t)row * N + n0 + wn + l16;
                for (int nt = 0; nt < 4; ++nt)
                    crow[nt * 16] = acc[mt][nt][r];
            } else {
                u16* crow = (u16*)Cout + (size_t)row * N + n0 + wn + l16;
                for (int nt = 0; nt < 4; ++nt)
                    crow[nt * 16] = f2bf(acc[mt][nt][r]);
            }
        }
}

// ---------------- flash attention, causal + ALiBi ----------------
// R9: R8 structure (S^T / O^T, per-lane softmax, swizzled stride-64 LDS, K-DMA,
// V perm-packed publish) with the K-loop UNROLLED x2 so LDS buffer bases are
// compile-time literals; all swizzled LDS offsets precomputed; global pointers
// strength-reduced; Ps packing via rbf+v_perm (2+1 insts/pair).
#define ATL(KT, CUR, NXT, MORE)                                                     \
{                                                                                   \
    u32x4 vw0, vw1;                                                                 \
    if (MORE) {                                                                     \
        async16(gk0, &KsB[NXT][kd0]);                                               \
        async16(gk1, &KsB[NXT][kd1]);                                               \
        vw0 = *(const u32x4*)gv0;                                                   \
        vw1 = *(const u32x4*)gv1;                                                   \
        gk0 += TS; gk1 += TS; gv0 += TS; gv1 += TS;                                 \
    }                                                                               \
    f32x4 st[4];                                                                    \
    _Pragma("unroll")                                                               \
    for (int nt = 0; nt < 4; ++nt) {                                                \
        bf16x8 bk0 = *(const bf16x8*)&KsB[CUR][koff[nt][0]];                        \
        bf16x8 bk1 = *(const bf16x8*)&KsB[CUR][koff[nt][1]];                        \
        f32x4 a_ = mfma16(bk0, qf[0], zero);                                        \
        st[nt] = mfma16(bk1, qf[1], a_);                                            \
    }                                                                               \
    const float b0 = slope2 * (float)((KT) * 64);                                   \
    _Pragma("unroll")                                                               \
    for (int nt = 0; nt < 4; ++nt)                                                  \
        for (int r = 0; r < 4; ++r)                                                 \
            st[nt][r] = st[nt][r] * scale2 + pre[nt][r];                            \
    if ((KT) == qb) {                                                               \
        const int loc = irow - (KT) * 64;                                           \
        _Pragma("unroll")                                                           \
        for (int nt = 0; nt < 4; ++nt)                                              \
            for (int r = 0; r < 4; ++r)                                             \
                st[nt][r] = (nt * 16 + quad * 4 + r <= loc) ? st[nt][r] : -1e30f;   \
    }                                                                               \
    f32x4 mv = vmax4(vmax4(st[0], st[1]), vmax4(st[2], st[3]));                     \
    float tm = fmaxf(fmaxf(mv[0], mv[1]), fmaxf(mv[2], mv[3]));                     \
    tm = fmaxf(tm, __shfl_xor(tm, 16, 64));                                         \
    tm = fmaxf(tm, __shfl_xor(tm, 32, 64));                                         \
    float mnew = fmaxf(mst, tm + b0);                                               \
    float alpha = exp2f(mst - mnew);                                                \
    mst = mnew;                                                                     \
    const float dsub = mnew - b0;                                                   \
    _Pragma("unroll")                                                               \
    for (int nt = 0; nt < 4; ++nt)                                                  \
        for (int r = 0; r < 4; ++r)                                                 \
            st[nt][r] = exp2f(st[nt][r] - dsub);                                    \
    f32x4 sv = (st[0] + st[1]) + (st[2] + st[3]);                                   \
    lst = lst * alpha + ((sv[0] + sv[1]) + (sv[2] + sv[3]));                        \
    _Pragma("unroll")                                                               \
    for (int nt = 0; nt < 4; ++nt) {                                                \
        u32x2 w;                                                                    \
        w[0] = __builtin_amdgcn_perm(rbf(st[nt][1]), rbf(st[nt][0]), 0x07060302u);  \
        w[1] = __builtin_amdgcn_perm(rbf(st[nt][3]), rbf(st[nt][2]), 0x07060302u);  \
        *(u32x2*)&Psh[psw[nt]] = w;                                                 \
    }                                                                               \
    _Pragma("unroll")                                                               \
    for (int nt = 0; nt < 4; ++nt)                                                  \
        for (int r = 0; r < 4; ++r) oacc[nt][r] *= alpha;                           \
    bf16x8 pa0 = *(const bf16x8*)&Psh[ap0];                                         \
    bf16x8 pa1 = *(const bf16x8*)&Psh[ap1];                                         \
    _Pragma("unroll")                                                               \
    for (int nt = 0; nt < 4; ++nt) {                                                \
        bf16x8 av0 = *(const bf16x8*)&VtsB[CUR][koff[nt][0]];                       \
        bf16x8 av1 = *(const bf16x8*)&VtsB[CUR][koff[nt][1]];                       \
        oacc[nt] = mfma16(av0, pa0, oacc[nt]);                                      \
        oacc[nt] = mfma16(av1, pa1, oacc[nt]);                                      \
    }                                                                               \
    if (MORE) {                                                                     \
        _Pragma("unroll")                                                           \
        for (int j = 0; j < 8; ++j) {                                               \
            unsigned sel = (j & 1) ? 0x07060302u : 0x05040100u;                     \
            *(unsigned*)&VtsB[NXT][vpub[j]] =                                       \
                __builtin_amdgcn_perm(vw1[j >> 1], vw0[j >> 1], sel);               \
        }                                                                           \
    }                                                                               \
    __syncthreads();                                                                \
}

__global__ __launch_bounds__(256, 4)
void attn_k(const u16* qkv, u16* o, int ostride) {
    __shared__ alignas(16) u16 KsB [2][64 * 64];
    __shared__ alignas(16) u16 VtsB[2][64 * 64];
    __shared__ alignas(16) u16 Psh [64 * 64];
    const int x = blockIdx.x;
    const int qb = 31 - (x >> 5);          // heavy blocks first
    const int bh = x & 31;
    const int b = bh >> 4, h = bh & 15;
    const int tid = threadIdx.x;
    const int wave = tid >> 6, lane = tid & 63;
    const int quad = lane >> 4, l16 = lane & 15;
    const float LOG2E = 1.44269504f;
    const float slope2 = exp2f(-0.5f * (float)(h + 1)) * LOG2E;
    const float scale2 = 0.125f * LOG2E;
    const size_t seq0 = (size_t)b * 2048;
    const int row0 = qb * 64 + wave * 16;
    const int irow = row0 + l16;

    bf16x8 qf[2];
    {
        const u16* qrow = qkv + (seq0 + irow) * 3072 + h * 64;
        qf[0] = *(const bf16x8*)(qrow + quad * 8);
        qf[1] = *(const bf16x8*)(qrow + 32 + quad * 8);
    }

    float pre[4][4];
    #pragma unroll
    for (int nt = 0; nt < 4; ++nt)
        for (int r = 0; r < 4; ++r)
            pre[nt][r] = slope2 * (float)(nt * 16 + quad * 4 + r);

    // precomputed LDS u16-index offsets (kt-invariant; K and Vt share the layout)
    int koff[4][2];
    #pragma unroll
    for (int nt = 0; nt < 4; ++nt) {
        int krow = nt * 16 + l16;
        koff[nt][0] = krow * 64 + ((quad ^ (krow & 7)) << 3);
        koff[nt][1] = krow * 64 + (((4 + quad) ^ (krow & 7)) << 3);
    }
    const int q = wave * 16 + l16;
    int psw[4];
    #pragma unroll
    for (int nt = 0; nt < 4; ++nt)
        psw[nt] = q * 64 + (((nt * 2 + (quad >> 1)) ^ (l16 & 7)) << 3) + (quad & 1) * 4;
    const int ap0 = q * 64 + ((quad ^ (l16 & 7)) << 3);
    const int ap1 = q * 64 + (((4 + quad) ^ (l16 & 7)) << 3);

    const int tpair = tid & 31;
    const int vd0 = ((tid * 2) >> 6) * 8;
    const int k0p = (tid * 2) & 63;
    int vpub[8];
    #pragma unroll
    for (int j = 0; j < 8; ++j) {
        int d = vd0 + j;
        vpub[j] = d * 64 + (((tpair >> 2) ^ (d & 7)) << 3) + (tpair & 3) * 2;
    }

    const int r0p = wave * 16 + (lane >> 3);
    const int kd0 = (wave * 16) * 64;
    const int kd1 = (wave * 16 + 8) * 64;
    const size_t TS = (size_t)64 * 3072;
    const u16* kbase = qkv + seq0 * 3072 + 1024 + h * 64;
    const u16* gk0 = kbase + (size_t)r0p * 3072 + (((lane & 7) ^ (r0p & 7)) << 3);
    const u16* gk1 = kbase + (size_t)(r0p + 8) * 3072 + (((lane & 7) ^ ((r0p + 8) & 7)) << 3);
    const u16* gv0 = kbase + 1024 + (size_t)k0p * 3072 + vd0;
    const u16* gv1 = gv0 + 3072;

    // ---- stage tile 0 ----
    async16(gk0, &KsB[0][kd0]);
    async16(gk1, &KsB[0][kd1]);
    {
        u32x4 vw0 = *(const u32x4*)gv0;
        u32x4 vw1 = *(const u32x4*)gv1;
        #pragma unroll
        for (int j = 0; j < 8; ++j) {
            unsigned sel = (j & 1) ? 0x07060302u : 0x05040100u;
            *(unsigned*)&VtsB[0][vpub[j]] =
                __builtin_amdgcn_perm(vw1[j >> 1], vw0[j >> 1], sel);
        }
    }
    gk0 += TS; gk1 += TS; gv0 += TS; gv1 += TS;
    __syncthreads();

    float mst = -1e30f, lst = 0.f;
    f32x4 oacc[4];
    const f32x4 zero = {0.f, 0.f, 0.f, 0.f};
    for (int nt = 0; nt < 4; ++nt) oacc[nt] = zero;

    const int ktiles = qb + 1;
    int kt = 0;
    while (kt + 2 <= ktiles) {
        ATL(kt, 0, 1, true)
        ATL(kt + 1, 1, 0, (kt + 2 < ktiles))
        kt += 2;
    }
    if (kt < ktiles)
        ATL(kt, 0, 1, false)

    float l2 = lst + __shfl_xor(lst, 16, 64);
    float l4 = l2 + __shfl_xor(l2, 32, 64);
    float inv = 1.f / l4;
    u16* orow = o + (seq0 + row0 + l16) * (size_t)ostride + h * 64 + quad * 4;
    for (int nt = 0; nt < 4; ++nt) {
        u16x4 w;
        for (int r = 0; r < 4; ++r) w[r] = bf16c(oacc[nt][r] * inv);
        *(u16x4*)(orow + nt * 16) = w;
    }
}

// ---------------- launch ----------------
// Inputs fp32, output fp32. ws: wqkvT 6 MiB | wprojT 2 MiB | qkv 24 MiB (32 MiB peak;
// safe — R2 ran bit-identical with 50.6 MiB in use). xb lives in d_out's first 8 MiB.
extern "C" void kernel_launch(void* const* d_in, const int* in_sizes, int n_in,
                              void* d_out, int out_size, void* d_ws, size_t ws_size,
                              hipStream_t stream) {
    (void)in_sizes; (void)n_in; (void)out_size; (void)ws_size;
    const float* x     = (const float*)d_in[0];   // [4096][1024]
    const float* wqkv  = (const float*)d_in[1];   // [1024][3072]
    const float* wproj = (const float*)d_in[2];   // [1024][1024]

    u16* wqkvT  = (u16*)d_ws;                              // 6 MiB
    u16* wprojT = wqkvT + (size_t)3072 * 1024;             // 2 MiB
    u16* qkv    = wprojT + (size_t)1024 * 1024;            // 24 MiB
    u16* xb     = (u16*)d_out;                             // scratch in d_out

    prep_k<<<dim3(3072), 256, 0, stream>>>(x, wqkv, wproj, xb, wqkvT, wprojT);
    gemm_bt<<<dim3(32, 24), 256, 0, stream>>>(xb, wqkvT, qkv, 4096, 3072, 1024, 1024, 0);
    attn_k<<<dim3(1024), 256, 0, stream>>>(qkv, qkv, 3072);
    gemm_bt<<<dim3(32, 8), 256, 0, stream>>>(qkv, wprojT, d_out, 4096, 1024, 1024, 3072, 1);
}

// Round 10
// 182.307 us; speedup vs baseline: 1.2019x; 1.2019x over previous
//
#include <hip/hip_runtime.h>
#include <cstdint>
#include <cstddef>

typedef unsigned short u16;
typedef __bf16 bf16x8 __attribute__((ext_vector_type(8)));
typedef float f32x4 __attribute__((ext_vector_type(4)));
typedef u16 u16x4 __attribute__((ext_vector_type(4)));
typedef unsigned int u32x2 __attribute__((ext_vector_type(2)));
typedef unsigned int u32x4 __attribute__((ext_vector_type(4)));

#define DEV __device__ __forceinline__

DEV u16 f2bf(float f) {
    union { float f; unsigned u; } un; un.f = f;
    unsigned u = un.u;
    return (u16)((u + 0x7fffu + ((u >> 16) & 1u)) >> 16);
}

DEV u16 bf16c(float f) {            // HW convert (RNE)
    __bf16 b = (__bf16)f;
    u16 r; __builtin_memcpy(&r, &b, 2); return r;
}

DEV f32x4 mfma16(bf16x8 a, bf16x8 b, f32x4 c) {
    return __builtin_amdgcn_mfma_f32_16x16x32_bf16(a, b, c, 0, 0, 0);
}

DEV f32x4 vmax4(f32x4 a, f32x4 b) {
    f32x4 r;
    r[0] = fmaxf(a[0], b[0]); r[1] = fmaxf(a[1], b[1]);
    r[2] = fmaxf(a[2], b[2]); r[3] = fmaxf(a[3], b[3]);
    return r;
}

DEV void async16(const u16* g, u16* l) {
    __builtin_amdgcn_global_load_lds(
        (__attribute__((address_space(1))) unsigned int*)(void*)g,
        (__attribute__((address_space(3))) unsigned int*)(void*)l,
        16, 0, 0);
}

// ---------------- fused prep: x cast + both weight transposes ----------------
DEV void trans_body(const float* __restrict__ src, u16* __restrict__ dst,
                    int R, int C, int bx, int by, int tid, u16 (*t)[65]) {
    const int c0 = bx * 64, r0 = by * 64;
    for (int i = 0; i < 4; ++i) {
        int e = (i * 256 + tid) * 4;
        int r = e >> 6, c = e & 63;
        f32x4 v = *(const f32x4*)(src + (size_t)(r0 + r) * C + (c0 + c));
        t[r][c] = f2bf(v[0]); t[r][c + 1] = f2bf(v[1]);
        t[r][c + 2] = f2bf(v[2]); t[r][c + 3] = f2bf(v[3]);
    }
    __syncthreads();
    for (int i = 0; i < 4; ++i) {
        int e = (i * 256 + tid) * 4;
        int ro = e >> 6, co = e & 63;
        u16x4 v;
        v[0] = t[co][ro]; v[1] = t[co + 1][ro]; v[2] = t[co + 2][ro]; v[3] = t[co + 3][ro];
        *(u16x4*)(dst + (size_t)(c0 + ro) * R + (r0 + co)) = v;
    }
}

__global__ __launch_bounds__(256)
void prep_k(const float* __restrict__ x, const float* __restrict__ wqkv,
            const float* __restrict__ wproj, u16* __restrict__ xb,
            u16* __restrict__ wqkvT, u16* __restrict__ wprojT) {
    __shared__ u16 t[64][65];
    const int bid = blockIdx.x, tid = threadIdx.x;
    if (bid < 2048) {                 // x: fp32 -> bf16, 8 elems/thread
        int i = bid * 256 + tid;
        const float* s = x + (size_t)i * 8;
        f32x4 a = *(const f32x4*)s;
        f32x4 b = *(const f32x4*)(s + 4);
        u16 o[8];
        o[0] = f2bf(a[0]); o[1] = f2bf(a[1]); o[2] = f2bf(a[2]); o[3] = f2bf(a[3]);
        o[4] = f2bf(b[0]); o[5] = f2bf(b[1]); o[6] = f2bf(b[2]); o[7] = f2bf(b[3]);
        u16x4* d = (u16x4*)(xb + (size_t)i * 8);
        d[0] = *(u16x4*)&o[0]; d[1] = *(u16x4*)&o[4];
    } else if (bid < 2816) {          // wqkv [1024][3072] -> wqkvT [3072][1024]
        int i = bid - 2048;
        trans_body(wqkv, wqkvT, 1024, 3072, i % 48, i / 48, tid, t);
    } else {                          // wproj [1024][1024] -> wprojT
        int i = bid - 2816;
        trans_body(wproj, wprojT, 1024, 1024, i % 16, i / 16, tid, t);
    }
}

// ---------------- C[M][N] = A[M][K] @ Bt[N][K]^T, bf16 in, fp32 acc ----------------
__global__ __launch_bounds__(256, 3)
void gemm_bt(const u16* __restrict__ A, const u16* __restrict__ Bt,
             void* __restrict__ Cout, int M, int N, int K, int lda, int of32) {
    __shared__ alignas(16) u16 As[128 * 32];
    __shared__ alignas(16) u16 Bs[128 * 32];
    const int tid = threadIdx.x;
    const int wave = tid >> 6, lane = tid & 63;
    const int quad = lane >> 4, l16 = lane & 15;
    const int m0 = blockIdx.x * 128, n0 = blockIdx.y * 128;
    const int wm = (wave & 1) * 64, wn = (wave >> 1) * 64;

    const f32x4 zero = {0.f, 0.f, 0.f, 0.f};
    f32x4 acc[4][4];
    for (int i = 0; i < 4; ++i) for (int j = 0; j < 4; ++j) acc[i][j] = zero;

    for (int k0 = 0; k0 < K; k0 += 32) {
        __syncthreads();
        for (int p = 0; p < 2; ++p) {
            int s = p * 256 + tid;
            int row = s >> 2, kcs = s & 3;
            int kc = kcs ^ ((row >> 1) & 3);
            async16(A + (size_t)(m0 + row) * lda + k0 + kc * 8, &As[(p * 256 + wave * 64) * 8]);
            async16(Bt + (size_t)(n0 + row) * K + k0 + kc * 8, &Bs[(p * 256 + wave * 64) * 8]);
        }
        __syncthreads();

        bf16x8 af[4], bfr[4];
        for (int mt = 0; mt < 4; ++mt) {
            int row = wm + mt * 16 + l16;
            int ci = (row << 2) | (quad ^ ((row >> 1) & 3));
            af[mt] = *(const bf16x8*)&As[ci * 8];
        }
        for (int nt = 0; nt < 4; ++nt) {
            int col = wn + nt * 16 + l16;
            int ci = (col << 2) | (quad ^ ((col >> 1) & 3));
            bfr[nt] = *(const bf16x8*)&Bs[ci * 8];
        }
        for (int mt = 0; mt < 4; ++mt)
            for (int nt = 0; nt < 4; ++nt)
                acc[mt][nt] = mfma16(af[mt], bfr[nt], acc[mt][nt]);
    }

    for (int mt = 0; mt < 4; ++mt)
        for (int r = 0; r < 4; ++r) {
            int row = m0 + wm + mt * 16 + quad * 4 + r;
            if (of32) {
                float* crow = (float*)Cout + (size_t)row * N + n0 + wn + l16;
                for (int nt = 0; nt < 4; ++nt)
                    crow[nt * 16] = acc[mt][nt][r];
            } else {
                u16* crow = (u16*)Cout + (size_t)row * N + n0 + wn + l16;
                for (int nt = 0; nt < 4; ++nt)
                    crow[nt * 16] = f2bf(acc[mt][nt][r]);
            }
        }
}

// ---------------- flash attention, causal + ALiBi ----------------
// R10 = EXACT R8 structure (proven 57 µs): S^T/O^T per-lane softmax, swizzled
// stride-64 LDS, K via DMA, runtime cur/nxt indexing, inline offset math (keeps
// arch-VGPR <= 64 — R9's precomputed-offset arrays + x2 unroll caused scratch
// spills: WRITE_SIZE 13->35 MB). Single micro-change: V loaded as u32x4 and
// packed with v_perm_b32 (1 instr/word vs extract+shift+or; same 4 VGPRs).
__global__ __launch_bounds__(256, 4)
void attn_k(const u16* qkv, u16* o, int ostride) {
    __shared__ alignas(16) u16 KsB [2][64 * 64];
    __shared__ alignas(16) u16 VtsB[2][64 * 64];
    __shared__ alignas(16) u16 Psh [64 * 64];
    const int x = blockIdx.x;
    const int qb = 31 - (x >> 5);          // heavy blocks first (LPT)
    const int bh = x & 31;
    const int b = bh >> 4, h = bh & 15;
    const int tid = threadIdx.x;
    const int wave = tid >> 6, lane = tid & 63;
    const int quad = lane >> 4, l16 = lane & 15;
    const float LOG2E = 1.44269504f;
    const float slope2 = exp2f(-0.5f * (float)(h + 1)) * LOG2E;
    const float scale2 = 0.125f * LOG2E;
    const size_t seq0 = (size_t)b * 2048;
    const int row0 = qb * 64 + wave * 16;
    const int irow = row0 + l16;           // this lane's softmax row (q = l16)

    // Q fragments (MFMA B operand for S^T: n=l16=q, k=quad*8+j)
    bf16x8 qf[2];
    {
        const u16* qrow = qkv + (seq0 + irow) * 3072 + h * 64;
        qf[0] = *(const bf16x8*)(qrow + quad * 8);
        qf[1] = *(const bf16x8*)(qrow + 32 + quad * 8);
    }

    // hoisted ALiBi bias for this lane's 16 (nt,r) slots (kt-invariant part)
    float pre[4][4];
    for (int nt = 0; nt < 4; ++nt)
        for (int r = 0; r < 4; ++r)
            pre[nt][r] = slope2 * (float)(nt * 16 + quad * 4 + r);

    float mst = -1e30f, lst = 0.f;         // per-lane running max / partial sum
    f32x4 oacc[4];                          // O^T: col q=l16, row d=nt*16+quad*4+r
    const f32x4 zero = {0.f, 0.f, 0.f, 0.f};
    for (int nt = 0; nt < 4; ++nt) oacc[nt] = zero;

    const int ktiles = qb + 1;
    const u16* kbase = qkv + seq0 * 3072 + 1024 + h * 64;
    const u16* vbase = kbase + 1024;
    const int tpair = tid & 31;            // V pair word index within row
    const int vd0 = ((tid * 2) >> 6) * 8;  // V d-chunk base for this thread
    const int k0p = (tid * 2) & 63;        // first of the thread's key pair

    // ---- stage tile 0 ----
    for (int p = 0; p < 2; ++p) {          // K via swizzled DMA
        int row = wave * 16 + p * 8 + (lane >> 3);
        int kc = (lane & 7) ^ (row & 7);
        async16(kbase + (size_t)row * 3072 + kc * 8, &KsB[0][(wave * 16 + p * 8) * 64]);
    }
    u32x4 vw0, vw1;
    vw0 = *(const u32x4*)(vbase + (size_t)k0p * 3072 + vd0);
    vw1 = *(const u32x4*)(vbase + (size_t)(k0p + 1) * 3072 + vd0);
    for (int j = 0; j < 8; ++j) {
        unsigned sel = (j & 1) ? 0x07060302u : 0x05040100u;
        unsigned w = __builtin_amdgcn_perm(vw1[j >> 1], vw0[j >> 1], sel);
        int d = vd0 + j;
        *(unsigned*)&VtsB[0][d * 64 + (((tpair >> 2) ^ (d & 7)) << 3) + (tpair & 3) * 2] = w;
    }
    __syncthreads();

    for (int kt = 0; kt < ktiles; ++kt) {
        const int cur = kt & 1, nxt = cur ^ 1;
        const bool more = (kt + 1 < ktiles);
        if (more) {    // K DMA straight into nxt; V into registers
            const u16* kb = kbase + (size_t)(kt + 1) * 64 * 3072;
            for (int p = 0; p < 2; ++p) {
                int row = wave * 16 + p * 8 + (lane >> 3);
                int kc = (lane & 7) ^ (row & 7);
                async16(kb + (size_t)row * 3072 + kc * 8, &KsB[nxt][(wave * 16 + p * 8) * 64]);
            }
            const u16* vb = vbase + (size_t)(kt + 1) * 64 * 3072;
            vw0 = *(const u32x4*)(vb + (size_t)k0p * 3072 + vd0);
            vw1 = *(const u32x4*)(vb + (size_t)(k0p + 1) * 3072 + vd0);
        }

        // S^T = K @ Q^T (C-layout: col=l16=q, row=quad*4+r=key within nt*16 group)
        f32x4 st[4];
        for (int nt = 0; nt < 4; ++nt) st[nt] = zero;
        for (int nt = 0; nt < 4; ++nt)
            for (int ks = 0; ks < 2; ++ks) {
                int krow = nt * 16 + l16;
                bf16x8 bk = *(const bf16x8*)&KsB[cur][krow * 64 + (((ks * 4 + quad) ^ (krow & 7)) << 3)];
                st[nt] = mfma16(bk, qf[ks], st[nt]);
            }

        // bias (biased domain: true score = st*scale2 + pre + b0, b0 = slope2*64*kt)
        const float b0 = slope2 * (float)(kt * 64);
        for (int nt = 0; nt < 4; ++nt)
            for (int r = 0; r < 4; ++r)
                st[nt][r] = st[nt][r] * scale2 + pre[nt][r];
        if (kt == qb) {    // causal mask, diagonal tile only
            const int loc = irow - kt * 64;     // key_local <= loc
            for (int nt = 0; nt < 4; ++nt)
                for (int r = 0; r < 4; ++r)
                    st[nt][r] = (nt * 16 + quad * 4 + r <= loc) ? st[nt][r] : -1e30f;
        }

        // row max: 16 in-register + 2 cross-quad shuffles
        f32x4 mv = vmax4(vmax4(st[0], st[1]), vmax4(st[2], st[3]));
        float tm = fmaxf(fmaxf(mv[0], mv[1]), fmaxf(mv[2], mv[3]));
        tm = fmaxf(tm, __shfl_xor(tm, 16, 64));
        tm = fmaxf(tm, __shfl_xor(tm, 32, 64));
        float mnew = fmaxf(mst, tm + b0);       // true-domain running max
        float alpha = exp2f(mst - mnew);
        mst = mnew;
        const float dsub = mnew - b0;           // subtract in biased domain

        for (int nt = 0; nt < 4; ++nt)
            for (int r = 0; r < 4; ++r)
                st[nt][r] = exp2f(st[nt][r] - dsub);
        f32x4 sv = (st[0] + st[1]) + (st[2] + st[3]);
        lst = lst * alpha + ((sv[0] + sv[1]) + (sv[2] + sv[3]));

        // Ps[q][k] <- packed bf16 b64 per nt (intra-wave rows, no barrier needed)
        {
            const int q = wave * 16 + l16;
            for (int nt = 0; nt < 4; ++nt) {
                u32x2 w;
                w[0] = (unsigned)bf16c(st[nt][0]) | ((unsigned)bf16c(st[nt][1]) << 16);
                w[1] = (unsigned)bf16c(st[nt][2]) | ((unsigned)bf16c(st[nt][3]) << 16);
                int ch = ((nt * 2 + (quad >> 1)) ^ (l16 & 7));
                *(u32x2*)&Psh[q * 64 + (ch << 3) + (quad & 1) * 4] = w;
            }
        }

        // per-lane O^T rescale (alpha is for q = l16 — this lane's column)
        for (int nt = 0; nt < 4; ++nt)
            for (int r = 0; r < 4; ++r) oacc[nt][r] *= alpha;

        // O^T += mfma(A=Vt rows d, B=Ps rows q)
        {
            const int q = wave * 16 + l16;
            bf16x8 ap[2];
            ap[0] = *(const bf16x8*)&Psh[q * 64 + (((quad) ^ (l16 & 7)) << 3)];
            ap[1] = *(const bf16x8*)&Psh[q * 64 + (((4 + quad) ^ (l16 & 7)) << 3)];
            for (int nt = 0; nt < 4; ++nt) {
                int drow = nt * 16 + l16;
                for (int ks = 0; ks < 2; ++ks) {
                    bf16x8 av = *(const bf16x8*)&VtsB[cur][drow * 64 + (((ks * 4 + quad) ^ (drow & 7)) << 3)];
                    oacc[nt] = mfma16(av, ap[ks], oacc[nt]);
                }
            }
        }

        if (more) {    // publish V pairs into nxt (perm: 1 instr/word)
            for (int j = 0; j < 8; ++j) {
                unsigned sel = (j & 1) ? 0x07060302u : 0x05040100u;
                unsigned w = __builtin_amdgcn_perm(vw1[j >> 1], vw0[j >> 1], sel);
                int d = vd0 + j;
                *(unsigned*)&VtsB[nxt][d * 64 + (((tpair >> 2) ^ (d & 7)) << 3) + (tpair & 3) * 2] = w;
            }
        }
        __syncthreads();    // publish nxt K (DMA drained) + V; guard cur reuse
    }

    // final l across quads (per-lane), then write O[q][d] (lane q = l16)
    float l2 = lst + __shfl_xor(lst, 16, 64);
    float l4 = l2 + __shfl_xor(l2, 32, 64);
    float inv = 1.f / l4;
    u16* orow = o + (seq0 + row0 + l16) * (size_t)ostride + h * 64 + quad * 4;
    for (int nt = 0; nt < 4; ++nt) {
        u16x4 w;
        for (int r = 0; r < 4; ++r) w[r] = bf16c(oacc[nt][r] * inv);
        *(u16x4*)(orow + nt * 16) = w;
    }
}

// ---------------- launch ----------------
// Inputs fp32, output fp32. ws: wqkvT 6 MiB | wprojT 2 MiB | qkv 24 MiB.
// xb lives in d_out's first 8 MiB (dead before gemm2 writes).
extern "C" void kernel_launch(void* const* d_in, const int* in_sizes, int n_in,
                              void* d_out, int out_size, void* d_ws, size_t ws_size,
                              hipStream_t stream) {
    (void)in_sizes; (void)n_in; (void)out_size; (void)ws_size;
    const float* x     = (const float*)d_in[0];   // [4096][1024]
    const float* wqkv  = (const float*)d_in[1];   // [1024][3072]
    const float* wproj = (const float*)d_in[2];   // [1024][1024]

    u16* wqkvT  = (u16*)d_ws;                              // 6 MiB
    u16* wprojT = wqkvT + (size_t)3072 * 1024;             // 2 MiB
    u16* qkv    = wprojT + (size_t)1024 * 1024;            // 24 MiB
    u16* xb     = (u16*)d_out;                             // scratch in d_out

    prep_k<<<dim3(3072), 256, 0, stream>>>(x, wqkv, wproj, xb, wqkvT, wprojT);
    gemm_bt<<<dim3(32, 24), 256, 0, stream>>>(xb, wqkvT, qkv, 4096, 3072, 1024, 1024, 0);
    attn_k<<<dim3(1024), 256, 0, stream>>>(qkv, qkv, 3072);
    gemm_bt<<<dim3(32, 8), 256, 0, stream>>>(qkv, wprojT, d_out, 4096, 1024, 1024, 3072, 1);
}